// Round 4
// baseline (6763.071 us; speedup 1.0000x reference)
//
#include <hip/hip_runtime.h>
#include <hip/hip_bf16.h>
#include <math.h>
#include <stdint.h>

#define BATCH 128
#define SEQ   512
#define HID   1024

typedef __attribute__((ext_vector_type(8))) short  short8;
typedef __attribute__((ext_vector_type(4))) short  short4v;
typedef __attribute__((ext_vector_type(4))) float  floatx4;
typedef __attribute__((ext_vector_type(8))) __bf16 bf16x8;
typedef unsigned long long ull;

__device__ __forceinline__ float bf2f(unsigned short s) {
  union { unsigned u; float f; } v;
  v.u = ((unsigned)s) << 16;
  return v.f;
}
__device__ __forceinline__ short f2bf(float f) {
  union { float f; unsigned u; } v;
  v.f = f;
  unsigned r = 0x7FFFu + ((v.u >> 16) & 1u);   // round-to-nearest-even
  return (short)((v.u + r) >> 16);
}
__device__ __forceinline__ floatx4 MFMA(short8 a, short8 b, floatx4 c) {
  return __builtin_amdgcn_mfma_f32_16x16x32_bf16(
      __builtin_bit_cast(bf16x8, a), __builtin_bit_cast(bf16x8, b), c, 0, 0, 0);
}
// tanh(x) = (e^2x - 1)/(e^2x + 1); clamp keeps exp2 in range; rel err ~1e-6
__device__ __forceinline__ float fast_tanh(float x) {
  float cx = fminf(15.f, fmaxf(-15.f, x));
  float e  = __builtin_amdgcn_exp2f(cx * 2.8853900817779268f);  // e^(2x)
  return (e - 1.f) * __builtin_amdgcn_rcpf(e + 1.f);
}

// ---------------------------------------------------------------------------
// Transpose + fp32->bf16: out[n][k] = (bf16) in[k][n], both 1024x1024.
// ---------------------------------------------------------------------------
__global__ void k_transpose(const float* __restrict__ in, short* __restrict__ out) {
  __shared__ float tile[32][33];
  const int tx = threadIdx.x, ty = threadIdx.y;
  const int n0 = blockIdx.x << 5, k0 = blockIdx.y << 5;
  #pragma unroll
  for (int i = 0; i < 4; ++i)
    tile[ty + i * 8][tx] = in[(size_t)(k0 + ty + i * 8) * HID + n0 + tx];
  __syncthreads();
  #pragma unroll
  for (int i = 0; i < 4; ++i)
    out[(size_t)(n0 + ty + i * 8) * HID + k0 + tx] = f2bf(tile[tx][ty + i * 8]);
}

// ---------------------------------------------------------------------------
// xp[s][b][h] = bf16( x[b][s][:] @ W_xh + b_h )   (unchanged)
// ---------------------------------------------------------------------------
__global__ __launch_bounds__(256) void k_xp(const float* __restrict__ x,
                                            const short* __restrict__ wxh_t,
                                            const float* __restrict__ b_h,
                                            short* __restrict__ xp) {
  __shared__ __align__(16) char smem[33792];
  short* lds_a = (short*)smem;
  short* lds_b = (short*)(smem + 14336);
  float* lds_e = (float*)smem;

  const int tid  = threadIdx.x;
  const int lane = tid & 63;
  const int wave = tid >> 6;
  const int wm = wave >> 1, wn = wave & 1;
  const int quad = lane >> 4, l15 = lane & 15;
  const int mt = blockIdx.y, nt = blockIdx.x;
  const int b  = mt >> 2;
  const int s0 = (mt & 3) << 7;
  const int n0 = nt << 7;

  floatx4 acc[4][4] = {};
  const float* xbase = x + ((size_t)(b * SEQ + s0)) * HID;

  for (int kt = 0; kt < 32; ++kt) {
    const int k0 = kt << 5;
    #pragma unroll
    for (int i = 0; i < 4; ++i) {
      int idx = tid + (i << 8);
      int row = idx >> 3, q = idx & 7;
      float4 v = *(const float4*)(xbase + (size_t)row * HID + k0 + (q << 2));
      short4v o = { f2bf(v.x), f2bf(v.y), f2bf(v.z), f2bf(v.w) };
      *(short4v*)(lds_a + row * 56 + (q << 2)) = o;
    }
    #pragma unroll
    for (int i = 0; i < 2; ++i) {
      int idx = tid + (i << 8);
      int row = idx >> 2, q = idx & 3;
      *(uint4*)(lds_b + row * 56 + (q << 3)) =
          *(const uint4*)(wxh_t + (size_t)(n0 + row) * HID + k0 + (q << 3));
    }
    __syncthreads();
    short8 af[4], bfr[4];
    #pragma unroll
    for (int f = 0; f < 4; ++f)
      af[f] = *(const short8*)(lds_a + (wm * 64 + f * 16 + l15) * 56 + quad * 8);
    #pragma unroll
    for (int f = 0; f < 4; ++f)
      bfr[f] = *(const short8*)(lds_b + (wn * 64 + f * 16 + l15) * 56 + quad * 8);
    #pragma unroll
    for (int mf = 0; mf < 4; ++mf)
      #pragma unroll
      for (int nf = 0; nf < 4; ++nf)
        acc[mf][nf] = MFMA(af[mf], bfr[nf], acc[mf][nf]);
    __syncthreads();
  }

  for (int phase = 0; phase < 2; ++phase) {
    if (wm == phase) {
      #pragma unroll
      for (int mf = 0; mf < 4; ++mf)
        #pragma unroll
        for (int nf = 0; nf < 4; ++nf)
          #pragma unroll
          for (int r = 0; r < 4; ++r)
            lds_e[(mf * 16 + quad * 4 + r) * 132 + wn * 64 + nf * 16 + l15] =
                acc[mf][nf][r];
    }
    __syncthreads();
    #pragma unroll
    for (int i = 0; i < 8; ++i) {
      int idx = tid + (i << 8);
      int row = idx >> 5, c = (idx & 31) << 2;
      float4 v  = *(const float4*)(lds_e + row * 132 + c);
      float4 bh = *(const float4*)(b_h + n0 + c);
      short4v o = { f2bf(v.x + bh.x), f2bf(v.y + bh.y),
                    f2bf(v.z + bh.z), f2bf(v.w + bh.w) };
      int s = s0 + (phase << 6) + row;
      *(short4v*)(xp + ((size_t)s * BATCH + b) * HID + n0 + c) = o;
    }
    __syncthreads();
  }
}

// ---------------------------------------------------------------------------
// Persistent recurrence, flag-free epoch-tagged protocol.
// Grid = 128 WGs = 4 m-groups (32 batch rows) x 32 n-slices (32 cols).
// h lives in ws as 8-B atomic granules {2xbf16 | step-tag}. Producers store
// granules with tag t+1 (relaxed agent atomics -> LLC-coherent, no fences,
// no flags, no store drain). Consumers stage their group's 32x1024 slice by
// loading granules and retrying only those whose tag != t: detection and
// data transfer share ONE LLC round trip. WAR on the double buffer is safe
// by dataflow (writer at t+1 implies its whole group read buffer at t).
// Stage batches of 16 granules software-pipelined for load ILP; LDS h copy
// XOR-swizzled for conflict-free ds_read_b128 in the k-loop. Top-of-loop
// barrier is raw s_barrier (no vmcnt drain); mid barrier waits lgkm only.
// ---------------------------------------------------------------------------
__global__ __launch_bounds__(256, 1) void k_rnn(const short* __restrict__ xp,
                                                const short* __restrict__ whh_t,
                                                ull* __restrict__ hT,
                                                unsigned* __restrict__ hfin) {
  __shared__ __align__(16) short lds_w[32 * 1024];   // 64 KB W_hh^T slice
  __shared__ __align__(16) short lds_h[32 * 1024];   // 64 KB h(t) stage

  const int tid  = threadIdx.x;
  const int lane = tid & 63;
  const int wave = tid >> 6;
  const int wm = wave >> 1, wn = wave & 1;
  const int quad = lane >> 4, l15 = lane & 15;
  const int wg  = blockIdx.x;
  const int grp = wg >> 5;          // m-group 0..3
  const int nsl = wg & 31;          // n-slice 0..31
  const int m0  = grp << 5;         // batch-row base (32 rows)
  const int n0  = nsl << 5;         // hidden-col base (32 cols)

  #pragma unroll
  for (int i = 0; i < 16; ++i) {    // load W slice once, swizzled
    int idx = tid + (i << 8);
    int row = idx >> 7, q = idx & 127;
    *(uint4*)(lds_w + row * 1024 + ((q ^ (row & 7)) << 3)) =
        *(const uint4*)(whh_t + (size_t)(n0 + row) * HID + (q << 3));
  }

  const int nloc = wn * 16 + l15;           // col within 32-slice
  const int col  = n0 + nloc;               // absolute hidden col
  const int swz  = nloc & 7;
  const short* wrow = lds_w + nloc * 1024;
  const int lrow = wm * 16 + l15;           // local A row 0..31
  const int aswz = lrow & 7;
  const short* hrow = lds_h + lrow * 1024;
  const int erow = m0 + wm * 16 + quad * 4; // epilogue row base (global)

  // prefetch xp for t=0
  unsigned short xv[4], xn[4];
  #pragma unroll
  for (int r = 0; r < 4; ++r)
    xv[r] = *(const unsigned short*)(xp + ((size_t)(erow + r)) * HID + col);

  __syncthreads();                          // W staged

  ull va[16], vb[16];

  for (int t = 0; t < SEQ; ++t) {
    if (t > 0)
      __builtin_amdgcn_s_barrier();         // lds_h WAR guard only (no drain)

    // prefetch xp for t+1 (issued first; plain cached loads)
    if (t + 1 < SEQ) {
      #pragma unroll
      for (int r = 0; r < 4; ++r)
        xn[r] = *(const unsigned short*)(xp + ((size_t)(t + 1) * BATCH + erow + r) * HID + col);
    }

    const ull* src = hT + (size_t)(t & 1) * (BATCH * (HID / 2));
    const unsigned exp_tag = (unsigned)t;

    auto ld = [&](int b, ull* v) {
      #pragma unroll
      for (int g = 0; g < 16; ++g) {
        int idx = tid + ((b * 16 + g) << 8);          // granule id in slice
        int rl = idx >> 9, j = idx & 511;
        v[g] = __hip_atomic_load(src + (size_t)(m0 + rl) * 512 + j,
                                 __ATOMIC_RELAXED, __HIP_MEMORY_SCOPE_AGENT);
      }
    };
    auto pr = [&](int b, ull* v) {
      #pragma unroll
      for (int g = 0; g < 16; ++g) {
        int idx = tid + ((b * 16 + g) << 8);
        int rl = idx >> 9, j = idx & 511;
        const ull* ap = src + (size_t)(m0 + rl) * 512 + j;
        ull u = v[g];
        while ((unsigned)(u >> 32) != exp_tag) {      // retry stragglers only
          __builtin_amdgcn_s_sleep(1);
          u = __hip_atomic_load(ap, __ATOMIC_RELAXED, __HIP_MEMORY_SCOPE_AGENT);
        }
        *(unsigned*)(lds_h + rl * 1024 + (((j >> 2) ^ (rl & 7)) << 3) + ((j & 3) << 1)) =
            (unsigned)u;
      }
    };

    ld(0, va); ld(1, vb);
    pr(0, va); ld(2, va);
    pr(1, vb); ld(3, vb);
    pr(2, va); pr(3, vb);

    // mid barrier: ds_write visibility needs lgkmcnt(0) only (vmcnt free)
    __builtin_amdgcn_s_waitcnt(0xC07F);
    __builtin_amdgcn_s_barrier();

    // ---- k-loop: pure LDS, 4 split accumulator chains ----
    floatx4 ac0 = {0.f,0.f,0.f,0.f}, ac1 = {0.f,0.f,0.f,0.f};
    floatx4 ac2 = {0.f,0.f,0.f,0.f}, ac3 = {0.f,0.f,0.f,0.f};
    #pragma unroll
    for (int kb = 0; kb < 32; kb += 4) {
      #pragma unroll
      for (int j = 0; j < 4; ++j) {
        int kc = ((kb + j) << 2) + quad;    // 16-B chunk index 0..127
        short8 a = *(const short8*)(hrow + ((kc ^ aswz) << 3));
        short8 b = *(const short8*)(wrow + ((kc ^ swz) << 3));
        floatx4& ac = j == 0 ? ac0 : j == 1 ? ac1 : j == 2 ? ac2 : ac3;
        ac = MFMA(a, b, ac);
      }
    }
    floatx4 acc = (ac0 + ac1) + (ac2 + ac3);

    // ---- epilogue: xp add + tanh + tagged 8-B store of h(t+1) ----
    if (t != SEQ - 1) {
      ull* dst = hT + (size_t)((t + 1) & 1) * (BATCH * (HID / 2));
      #pragma unroll
      for (int r = 0; r < 4; ++r) {
        float v = fast_tanh(bf2f(xv[r]) + acc[r]);
        unsigned mine = (unsigned)(unsigned short)f2bf(v);
        unsigned partner = (unsigned)__shfl_xor((int)mine, 1);
        if ((l15 & 1) == 0) {
          ull g = ((ull)(unsigned)(t + 1) << 32) | (ull)(mine | (partner << 16));
          __hip_atomic_store(dst + (size_t)(erow + r) * 512 + (col >> 1), g,
                             __ATOMIC_RELAXED, __HIP_MEMORY_SCOPE_AGENT);
        }
      }
      #pragma unroll
      for (int r = 0; r < 4; ++r) xv[r] = xn[r];
    } else {                                 // final step: plain bf16 h_final
      #pragma unroll
      for (int r = 0; r < 4; ++r) {
        float v = fast_tanh(bf2f(xv[r]) + acc[r]);
        unsigned mine = (unsigned)(unsigned short)f2bf(v);
        unsigned partner = (unsigned)__shfl_xor((int)mine, 1);
        if ((l15 & 1) == 0)
          hfin[(size_t)(erow + r) * 512 + (col >> 1)] = mine | (partner << 16);
      }
    }
  }
}

// ---------------------------------------------------------------------------
// out = h_final @ W_hy + b_y  (fp32 out, 128x1024)   (unchanged)
// ---------------------------------------------------------------------------
__global__ __launch_bounds__(256) void k_out(const short* __restrict__ hfin,
                                             const short* __restrict__ why_t,
                                             const float* __restrict__ b_y,
                                             float* __restrict__ out) {
  __shared__ __align__(16) short lds_a[64 * 56];
  __shared__ __align__(16) short lds_b[64 * 56];
  const int tid = threadIdx.x, lane = tid & 63, wave = tid >> 6;
  const int wm = wave >> 1, wn = wave & 1, quad = lane >> 4, l15 = lane & 15;
  const int m0 = blockIdx.y << 6, n0 = blockIdx.x << 6;
  floatx4 acc[2][2] = {};
  for (int kt = 0; kt < 32; ++kt) {
    int k0 = kt << 5;
    int row = tid >> 2, q = tid & 3;
    *(uint4*)(lds_a + row * 56 + (q << 3)) =
        *(const uint4*)(hfin + (size_t)(m0 + row) * HID + k0 + (q << 3));
    *(uint4*)(lds_b + row * 56 + (q << 3)) =
        *(const uint4*)(why_t + (size_t)(n0 + row) * HID + k0 + (q << 3));
    __syncthreads();
    short8 a0 = *(const short8*)(lds_a + (wm * 32 + l15) * 56 + quad * 8);
    short8 a1 = *(const short8*)(lds_a + (wm * 32 + 16 + l15) * 56 + quad * 8);
    short8 b0 = *(const short8*)(lds_b + (wn * 32 + l15) * 56 + quad * 8);
    short8 b1 = *(const short8*)(lds_b + (wn * 32 + 16 + l15) * 56 + quad * 8);
    acc[0][0] = MFMA(a0, b0, acc[0][0]);
    acc[0][1] = MFMA(a0, b1, acc[0][1]);
    acc[1][0] = MFMA(a1, b0, acc[1][0]);
    acc[1][1] = MFMA(a1, b1, acc[1][1]);
    __syncthreads();
  }
  #pragma unroll
  for (int mf = 0; mf < 2; ++mf)
    #pragma unroll
    for (int nf = 0; nf < 2; ++nf)
      #pragma unroll
      for (int r = 0; r < 4; ++r) {
        int row = m0 + wm * 32 + mf * 16 + quad * 4 + r;
        int col = n0 + wn * 32 + nf * 16 + l15;
        out[(size_t)row * HID + col] = acc[mf][nf][r] + b_y[col];
      }
}

// ---------------------------------------------------------------------------
extern "C" void kernel_launch(void* const* d_in, const int* in_sizes, int n_in,
                              void* d_out, int out_size, void* d_ws, size_t ws_size,
                              hipStream_t stream) {
  const float* x   = (const float*)d_in[0];
  const float* wxh = (const float*)d_in[1];
  const float* whh = (const float*)d_in[2];
  const float* b_h = (const float*)d_in[3];
  const float* why = (const float*)d_in[4];
  const float* b_y = (const float*)d_in[5];
  float* out = (float*)d_out;

  char* ws = (char*)d_ws;
  const size_t sz_xp = (size_t)SEQ * BATCH * HID * 2;   // 128 MiB
  const size_t sz_w  = (size_t)HID * HID * 2;           // 2 MiB each
  const size_t sz_hT = (size_t)2 * BATCH * (HID / 2) * 8;  // 1 MiB tagged h
  short*    xp    = (short*)ws;
  short*    why_t = (short*)ws;                          // overlays xp (used after k_rnn)
  short*    wxh_t = (short*)(ws + sz_xp);
  short*    whh_t = (short*)(ws + sz_xp + sz_w);
  ull*      hT    = (ull*)(ws + sz_xp + 2 * sz_w);
  unsigned* hfin  = (unsigned*)(ws + sz_xp + 2 * sz_w + sz_hT);  // 256 KiB

  // zero tagged h buffers: tag 0 == h(0), value 0  (ws poisoned 0xAA)
  hipMemsetAsync(hT, 0, sz_hT, stream);

  dim3 tb(32, 8), tg(32, 32);
  k_transpose<<<tg, tb, 0, stream>>>(wxh, wxh_t);
  k_transpose<<<tg, tb, 0, stream>>>(whh, whh_t);

  k_xp<<<dim3(8, 512), 256, 0, stream>>>(x, wxh_t, b_h, xp);
  k_rnn<<<128, 256, 0, stream>>>(xp, whh_t, hT, hfin);

  k_transpose<<<tg, tb, 0, stream>>>(why, why_t);        // xp dead by now
  k_out<<<dim3(16, 2), 256, 0, stream>>>((const short*)hfin, why_t, b_y, out);
}

// Round 5
// 5757.933 us; speedup vs baseline: 1.1746x; 1.1746x over previous
//
#include <hip/hip_runtime.h>
#include <hip/hip_bf16.h>
#include <math.h>
#include <stdint.h>

#define BATCH 128
#define SEQ   512
#define HID   1024

typedef __attribute__((ext_vector_type(8))) short  short8;
typedef __attribute__((ext_vector_type(4))) short  short4v;
typedef __attribute__((ext_vector_type(4))) float  floatx4;
typedef __attribute__((ext_vector_type(8))) __bf16 bf16x8;
typedef unsigned long long ull;

__device__ __forceinline__ float bf2f(unsigned short s) {
  union { unsigned u; float f; } v;
  v.u = ((unsigned)s) << 16;
  return v.f;
}
__device__ __forceinline__ short f2bf(float f) {
  union { float f; unsigned u; } v;
  v.f = f;
  unsigned r = 0x7FFFu + ((v.u >> 16) & 1u);   // round-to-nearest-even
  return (short)((v.u + r) >> 16);
}
__device__ __forceinline__ floatx4 MFMA(short8 a, short8 b, floatx4 c) {
  return __builtin_amdgcn_mfma_f32_16x16x32_bf16(
      __builtin_bit_cast(bf16x8, a), __builtin_bit_cast(bf16x8, b), c, 0, 0, 0);
}
// tanh(x) = (e^2x - 1)/(e^2x + 1); clamp keeps exp2 in range
__device__ __forceinline__ float fast_tanh(float x) {
  float cx = fminf(15.f, fmaxf(-15.f, x));
  float e  = __builtin_amdgcn_exp2f(cx * 2.8853900817779268f);  // e^(2x)
  return (e - 1.f) * __builtin_amdgcn_rcpf(e + 1.f);
}
// 8-B load bypassing L1 (sc0), hitting the XCD-shared L2. Serial (inline
// vmcnt) — used only on the few-granule straggler path.
__device__ __forceinline__ ull load_sc0(const ull* p) {
  ull r;
  asm volatile("global_load_dwordx2 %0, %1, off sc0\n\ts_waitcnt vmcnt(0)"
               : "=v"(r) : "v"(p) : "memory");
  return r;
}

// ---------------------------------------------------------------------------
// Transpose + fp32->bf16: out[n][k] = (bf16) in[k][n], both 1024x1024.
// ---------------------------------------------------------------------------
__global__ void k_transpose(const float* __restrict__ in, short* __restrict__ out) {
  __shared__ float tile[32][33];
  const int tx = threadIdx.x, ty = threadIdx.y;
  const int n0 = blockIdx.x << 5, k0 = blockIdx.y << 5;
  #pragma unroll
  for (int i = 0; i < 4; ++i)
    tile[ty + i * 8][tx] = in[(size_t)(k0 + ty + i * 8) * HID + n0 + tx];
  __syncthreads();
  #pragma unroll
  for (int i = 0; i < 4; ++i)
    out[(size_t)(n0 + ty + i * 8) * HID + k0 + tx] = f2bf(tile[tx][ty + i * 8]);
}

// ---------------------------------------------------------------------------
// xp[s][b][h] = bf16( x[b][s][:] @ W_xh + b_h )   (unchanged)
// ---------------------------------------------------------------------------
__global__ __launch_bounds__(256) void k_xp(const float* __restrict__ x,
                                            const short* __restrict__ wxh_t,
                                            const float* __restrict__ b_h,
                                            short* __restrict__ xp) {
  __shared__ __align__(16) char smem[33792];
  short* lds_a = (short*)smem;
  short* lds_b = (short*)(smem + 14336);
  float* lds_e = (float*)smem;

  const int tid  = threadIdx.x;
  const int lane = tid & 63;
  const int wave = tid >> 6;
  const int wm = wave >> 1, wn = wave & 1;
  const int quad = lane >> 4, l15 = lane & 15;
  const int mt = blockIdx.y, nt = blockIdx.x;
  const int b  = mt >> 2;
  const int s0 = (mt & 3) << 7;
  const int n0 = nt << 7;

  floatx4 acc[4][4] = {};
  const float* xbase = x + ((size_t)(b * SEQ + s0)) * HID;

  for (int kt = 0; kt < 32; ++kt) {
    const int k0 = kt << 5;
    #pragma unroll
    for (int i = 0; i < 4; ++i) {
      int idx = tid + (i << 8);
      int row = idx >> 3, q = idx & 7;
      float4 v = *(const float4*)(xbase + (size_t)row * HID + k0 + (q << 2));
      short4v o = { f2bf(v.x), f2bf(v.y), f2bf(v.z), f2bf(v.w) };
      *(short4v*)(lds_a + row * 56 + (q << 2)) = o;
    }
    #pragma unroll
    for (int i = 0; i < 2; ++i) {
      int idx = tid + (i << 8);
      int row = idx >> 2, q = idx & 3;
      *(uint4*)(lds_b + row * 56 + (q << 3)) =
          *(const uint4*)(wxh_t + (size_t)(n0 + row) * HID + k0 + (q << 3));
    }
    __syncthreads();
    short8 af[4], bfr[4];
    #pragma unroll
    for (int f = 0; f < 4; ++f)
      af[f] = *(const short8*)(lds_a + (wm * 64 + f * 16 + l15) * 56 + quad * 8);
    #pragma unroll
    for (int f = 0; f < 4; ++f)
      bfr[f] = *(const short8*)(lds_b + (wn * 64 + f * 16 + l15) * 56 + quad * 8);
    #pragma unroll
    for (int mf = 0; mf < 4; ++mf)
      #pragma unroll
      for (int nf = 0; nf < 4; ++nf)
        acc[mf][nf] = MFMA(af[mf], bfr[nf], acc[mf][nf]);
    __syncthreads();
  }

  for (int phase = 0; phase < 2; ++phase) {
    if (wm == phase) {
      #pragma unroll
      for (int mf = 0; mf < 4; ++mf)
        #pragma unroll
        for (int nf = 0; nf < 4; ++nf)
          #pragma unroll
          for (int r = 0; r < 4; ++r)
            lds_e[(mf * 16 + quad * 4 + r) * 132 + wn * 64 + nf * 16 + l15] =
                acc[mf][nf][r];
    }
    __syncthreads();
    #pragma unroll
    for (int i = 0; i < 8; ++i) {
      int idx = tid + (i << 8);
      int row = idx >> 5, c = (idx & 31) << 2;
      float4 v  = *(const float4*)(lds_e + row * 132 + c);
      float4 bh = *(const float4*)(b_h + n0 + c);
      short4v o = { f2bf(v.x + bh.x), f2bf(v.y + bh.y),
                    f2bf(v.z + bh.z), f2bf(v.w + bh.w) };
      int s = s0 + (phase << 6) + row;
      *(short4v*)(xp + ((size_t)s * BATCH + b) * HID + n0 + c) = o;
    }
    __syncthreads();
  }
}

// ---------------------------------------------------------------------------
// Persistent recurrence, epoch-tagged dual-path protocol.
// 256 WGs = 8 groups (16 batch rows) x 32 n-slices (32 cols); group =
// blockIdx&7 so (per the round-robin dispatch heuristic) a group's 32 WGs
// co-reside on one XCD. h granules = {32-bit step tag | 2xbf16}. Producers
// dual-store each granule: plain store (dirty in local XCD L2, fast
// visibility) + agent store (HBM, global guarantee). Consumers tag-validate:
// batched plain loads -> bounded batched sc0 (L1-bypass) sweeps -> agent/HBM
// sweeps with sleep backoff. Correct for ANY placement (tags + HBM copy);
// fast when co-located. Per-thread adaptive fast/slow mode, re-probe every
// 16 steps. No fences, no flags, no store drains, no wbl2/inv anywhere.
// Tile per WG: 16 rows x 32 cols; waves: kw=wave>>1 (k-half), nw=wave&1
// (n-half); k-split partials reduced through 2 KB LDS.
// LDS: 64 KB W + 32 KB h + 2 KB reduce = 98 KB -> 1 WG/CU.
// ---------------------------------------------------------------------------
__global__ __launch_bounds__(256, 1) void k_rnn(const short* __restrict__ xp,
                                                const short* __restrict__ whh_t,
                                                ull* __restrict__ hS,
                                                ull* __restrict__ hC,
                                                unsigned* __restrict__ hfin) {
  __shared__ __align__(16) short lds_w[32 * 1024];   // 64 KB W_hh^T slice
  __shared__ __align__(16) short lds_h[16 * 1024];   // 32 KB h(t) stage
  __shared__ __align__(16) float lds_r[2 * 16 * 16]; // 2 KB k-split reduce

  const int tid  = threadIdx.x;
  const int lane = tid & 63;
  const int wave = tid >> 6;
  const int kw = wave >> 1, nw = wave & 1;
  const int quad = lane >> 4, l15 = lane & 15;
  const int wg  = blockIdx.x;
  const int grp = wg & 7;           // group (intended XCD) 0..7
  const int nsl = wg >> 3;          // n-slice 0..31
  const int m0  = grp << 4;         // batch-row base (16 rows)
  const int n0  = nsl << 5;         // hidden-col base (32 cols)

  #pragma unroll
  for (int i = 0; i < 16; ++i) {    // load W slice once, swizzled
    int idx = tid + (i << 8);
    int row = idx >> 7, q = idx & 127;
    *(uint4*)(lds_w + row * 1024 + ((q ^ (row & 7)) << 3)) =
        *(const uint4*)(whh_t + (size_t)(n0 + row) * HID + (q << 3));
  }

  const int nloc = nw * 16 + l15;           // col within 32-slice
  const int col  = n0 + nloc;               // absolute hidden col
  const int swz  = nloc & 7;
  const short* wrow = lds_w + nloc * 1024;
  const short* hrow = lds_h + l15 * 1024;   // A row = l15 (16 rows)
  const int aswz = l15 & 7;
  const int erow = m0 + quad * 4;           // epilogue row base (kw==0)

  // prefetch xp for t=0 (kw==0 waves own the epilogue)
  unsigned short xv[4], xn[4];
  if (kw == 0) {
    #pragma unroll
    for (int r = 0; r < 4; ++r)
      xv[r] = *(const unsigned short*)(xp + ((size_t)(erow + r)) * HID + col);
  }
  __syncthreads();                          // W staged

  ull va[16], vb[16];
  bool fast = true;                          // per-thread adaptive mode

  for (int t = 0; t < SEQ; ++t) {
    if (t > 0)
      __builtin_amdgcn_s_barrier();          // lds_h/lds_r WAR guard

    if (kw == 0 && t + 1 < SEQ) {            // xp(t+1) prefetch
      #pragma unroll
      for (int r = 0; r < 4; ++r)
        xn[r] = *(const unsigned short*)(xp + ((size_t)(t + 1) * BATCH + erow + r) * HID + col);
    }

    const size_t pofs = (size_t)(t & 1) * (BATCH * (HID / 2));
    const ull* srcS = hS + pofs;
    const ull* srcC = hC + pofs;
    const unsigned exp_tag = (unsigned)t;
    const bool try_fast = fast || ((t & 15) == 0);
    bool usedC = false;

    auto gofs = [&](int base_c, int g) -> size_t {
      int idx = tid + ((base_c + g) << 8);
      int rl = idx >> 9, j = idx & 511;
      return (size_t)(m0 + rl) * 512 + j;
    };
    auto lput = [&](int base_c, int g, unsigned payload) {
      int idx = tid + ((base_c + g) << 8);
      int rl = idx >> 9, j = idx & 511;
      *(unsigned*)(lds_h + rl * 1024 + (((j >> 2) ^ (rl & 7)) << 3) + ((j & 3) << 1)) = payload;
    };
    auto ld = [&](int base_c, ull* v) {       // attempt-1: batched loads
      #pragma unroll
      for (int g = 0; g < 16; ++g)
        v[g] = try_fast ? srcS[gofs(base_c, g)]
                        : __hip_atomic_load(srcC + gofs(base_c, g),
                                            __ATOMIC_RELAXED, __HIP_MEMORY_SCOPE_AGENT);
    };
    auto proc = [&](int base_c, ull* v) {
      unsigned pend = 0;
      #pragma unroll
      for (int g = 0; g < 16; ++g) {
        if ((unsigned)(v[g] >> 32) == exp_tag) lput(base_c, g, (unsigned)v[g]);
        else pend |= 1u << g;
      }
      if (try_fast) {                         // bounded L2 straggler sweeps
        for (int s = 0; s < 4 && pend; ++s) {
          if (s) __builtin_amdgcn_s_sleep(1);
          #pragma unroll
          for (int g = 0; g < 16; ++g)
            if (pend & (1u << g)) {
              ull u = load_sc0(srcS + gofs(base_c, g));
              if ((unsigned)(u >> 32) == exp_tag) {
                lput(base_c, g, (unsigned)u);
                pend &= ~(1u << g);
              }
            }
        }
      }
      int spins = 0;                          // HBM-guaranteed sweeps
      while (pend) {
        usedC = true;
        if (spins++) __builtin_amdgcn_s_sleep(1);
        #pragma unroll
        for (int g = 0; g < 16; ++g)
          if (pend & (1u << g)) {
            ull u = __hip_atomic_load(srcC + gofs(base_c, g),
                                      __ATOMIC_RELAXED, __HIP_MEMORY_SCOPE_AGENT);
            if ((unsigned)(u >> 32) == exp_tag) {
              lput(base_c, g, (unsigned)u);
              pend &= ~(1u << g);
            }
          }
      }
    };

    ld(0, va); ld(16, vb);
    proc(0, va); proc(16, vb);
    fast = try_fast && !usedC;

    // mid barrier: lds_h visibility needs lgkmcnt(0) only
    __builtin_amdgcn_s_waitcnt(0xC07F);
    __builtin_amdgcn_s_barrier();

    // ---- k-loop: per-wave k-half, 4 split accumulator chains ----
    floatx4 ac0 = {0.f,0.f,0.f,0.f}, ac1 = {0.f,0.f,0.f,0.f};
    floatx4 ac2 = {0.f,0.f,0.f,0.f}, ac3 = {0.f,0.f,0.f,0.f};
    #pragma unroll
    for (int kb = 0; kb < 4; ++kb) {
      #pragma unroll
      for (int j = 0; j < 4; ++j) {
        int kc = kw * 64 + ((kb * 4 + j) << 2) + quad;   // chunk 0..127
        short8 a = *(const short8*)(hrow + ((kc ^ aswz) << 3));
        short8 b = *(const short8*)(wrow + ((kc ^ swz) << 3));
        floatx4& ac = j == 0 ? ac0 : j == 1 ? ac1 : j == 2 ? ac2 : ac3;
        ac = MFMA(a, b, ac);
      }
    }
    floatx4 acc = (ac0 + ac1) + (ac2 + ac3);

    // ---- k-split reduction through LDS (kw=1 -> kw=0) ----
    if (kw == 1)
      *(floatx4*)(lds_r + nw * 256 + l15 * 16 + quad * 4) = acc;
    __builtin_amdgcn_s_waitcnt(0xC07F);
    __builtin_amdgcn_s_barrier();

    if (kw == 0) {
      acc += *(const floatx4*)(lds_r + nw * 256 + l15 * 16 + quad * 4);

      if (t != SEQ - 1) {                    // tagged dual store of h(t+1)
        const size_t qofs = (size_t)((t + 1) & 1) * (BATCH * (HID / 2));
        #pragma unroll
        for (int r = 0; r < 4; ++r) {
          float v = fast_tanh(bf2f(xv[r]) + acc[r]);
          unsigned mine = (unsigned)(unsigned short)f2bf(v);
          unsigned partner = (unsigned)__shfl_xor((int)mine, 1);
          if ((l15 & 1) == 0) {
            ull g = ((ull)(unsigned)(t + 1) << 32) | (ull)(mine | (partner << 16));
            size_t o = qofs + (size_t)(erow + r) * 512 + (col >> 1);
            __hip_atomic_store(hS + o, g, __ATOMIC_RELAXED,
                               __HIP_MEMORY_SCOPE_WORKGROUP);   // local L2 copy
            __hip_atomic_store(hC + o, g, __ATOMIC_RELAXED,
                               __HIP_MEMORY_SCOPE_AGENT);       // HBM guarantee
          }
        }
        #pragma unroll
        for (int r = 0; r < 4; ++r) xv[r] = xn[r];
      } else {                               // final step: plain bf16 h_final
        #pragma unroll
        for (int r = 0; r < 4; ++r) {
          float v = fast_tanh(bf2f(xv[r]) + acc[r]);
          unsigned mine = (unsigned)(unsigned short)f2bf(v);
          unsigned partner = (unsigned)__shfl_xor((int)mine, 1);
          if ((l15 & 1) == 0)
            hfin[(size_t)(erow + r) * 512 + (col >> 1)] = mine | (partner << 16);
        }
      }
    }
  }
}

// ---------------------------------------------------------------------------
// out = h_final @ W_hy + b_y  (fp32 out, 128x1024)   (unchanged)
// ---------------------------------------------------------------------------
__global__ __launch_bounds__(256) void k_out(const short* __restrict__ hfin,
                                             const short* __restrict__ why_t,
                                             const float* __restrict__ b_y,
                                             float* __restrict__ out) {
  __shared__ __align__(16) short lds_a[64 * 56];
  __shared__ __align__(16) short lds_b[64 * 56];
  const int tid = threadIdx.x, lane = tid & 63, wave = tid >> 6;
  const int wm = wave >> 1, wn = wave & 1, quad = lane >> 4, l15 = lane & 15;
  const int m0 = blockIdx.y << 6, n0 = blockIdx.x << 6;
  floatx4 acc[2][2] = {};
  for (int kt = 0; kt < 32; ++kt) {
    int k0 = kt << 5;
    int row = tid >> 2, q = tid & 3;
    *(uint4*)(lds_a + row * 56 + (q << 3)) =
        *(const uint4*)(hfin + (size_t)(m0 + row) * HID + k0 + (q << 3));
    *(uint4*)(lds_b + row * 56 + (q << 3)) =
        *(const uint4*)(why_t + (size_t)(n0 + row) * HID + k0 + (q << 3));
    __syncthreads();
    short8 a0 = *(const short8*)(lds_a + (wm * 32 + l15) * 56 + quad * 8);
    short8 a1 = *(const short8*)(lds_a + (wm * 32 + 16 + l15) * 56 + quad * 8);
    short8 b0 = *(const short8*)(lds_b + (wn * 32 + l15) * 56 + quad * 8);
    short8 b1 = *(const short8*)(lds_b + (wn * 32 + 16 + l15) * 56 + quad * 8);
    acc[0][0] = MFMA(a0, b0, acc[0][0]);
    acc[0][1] = MFMA(a0, b1, acc[0][1]);
    acc[1][0] = MFMA(a1, b0, acc[1][0]);
    acc[1][1] = MFMA(a1, b1, acc[1][1]);
    __syncthreads();
  }
  #pragma unroll
  for (int mf = 0; mf < 2; ++mf)
    #pragma unroll
    for (int nf = 0; nf < 2; ++nf)
      #pragma unroll
      for (int r = 0; r < 4; ++r) {
        int row = m0 + wm * 32 + mf * 16 + quad * 4 + r;
        int col = n0 + wn * 32 + nf * 16 + l15;
        out[(size_t)row * HID + col] = acc[mf][nf][r] + b_y[col];
      }
}

// ---------------------------------------------------------------------------
extern "C" void kernel_launch(void* const* d_in, const int* in_sizes, int n_in,
                              void* d_out, int out_size, void* d_ws, size_t ws_size,
                              hipStream_t stream) {
  const float* x   = (const float*)d_in[0];
  const float* wxh = (const float*)d_in[1];
  const float* whh = (const float*)d_in[2];
  const float* b_h = (const float*)d_in[3];
  const float* why = (const float*)d_in[4];
  const float* b_y = (const float*)d_in[5];
  float* out = (float*)d_out;

  char* ws = (char*)d_ws;
  const size_t sz_xp = (size_t)SEQ * BATCH * HID * 2;      // 128 MiB
  const size_t sz_w  = (size_t)HID * HID * 2;              // 2 MiB each
  const size_t sz_h  = (size_t)2 * BATCH * (HID / 2) * 8;  // 1 MiB per copy
  short*    xp    = (short*)ws;
  short*    why_t = (short*)ws;                            // overlays xp
  short*    wxh_t = (short*)(ws + sz_xp);
  short*    whh_t = (short*)(ws + sz_xp + sz_w);
  ull*      hS    = (ull*)(ws + sz_xp + 2 * sz_w);          // L2-seed copy
  ull*      hC    = (ull*)(ws + sz_xp + 2 * sz_w + sz_h);   // coherent copy
  unsigned* hfin  = (unsigned*)(ws + sz_xp + 2 * sz_w + 2 * sz_h);

  // zero both tagged h copies: tag 0 == step 0, h = 0
  hipMemsetAsync(hS, 0, 2 * sz_h, stream);

  dim3 tb(32, 8), tg(32, 32);
  k_transpose<<<tg, tb, 0, stream>>>(wxh, wxh_t);
  k_transpose<<<tg, tb, 0, stream>>>(whh, whh_t);

  k_xp<<<dim3(8, 512), 256, 0, stream>>>(x, wxh_t, b_h, xp);
  k_rnn<<<256, 256, 0, stream>>>(xp, whh_t, hS, hC, hfin);

  k_transpose<<<tg, tb, 0, stream>>>(why, why_t);          // xp dead by now
  k_out<<<dim3(16, 2), 256, 0, stream>>>((const short*)hfin, why_t, b_y, out);
}